// Round 2
// baseline (1195.158 us; speedup 1.0000x reference)
//
#include <hip/hip_runtime.h>
#include <cstdint>
#include <cstddef>

// Problem constants
#define N0c 30000
#define F0c 128
#define Hc  256
#define Cc  16
#define N1c 3000
#define Bc  16
#define E0c 960000
#define E1c 48000
#define EPSc 1e-5f

static __host__ __device__ inline int cdiv_i(int a, int b) { return (a + b - 1) / b; }

// ---------------- graph preprocessing ----------------

__global__ void count_deg(const int* __restrict__ dst, int E, int* __restrict__ deg) {
    int e = blockIdx.x * blockDim.x + threadIdx.x;
    if (e < E) atomicAdd(&deg[dst[e]], 1);
}

__global__ void calc_dinv(const int* __restrict__ deg, float* __restrict__ dinv, int n) {
    int i = blockIdx.x * blockDim.x + threadIdx.x;
    if (i < n) dinv[i] = rsqrtf((float)(deg[i] + 1));  // +1 self loop, always > 0
}

// exclusive scan of cnt[n] -> rp[n] (+ rp[n]=total), 3-kernel multi-block scan (nb<=256)
__global__ void scan_block(const int* __restrict__ cnt, int n, int* __restrict__ rp,
                           int* __restrict__ blkSum) {
    __shared__ int sh[256];
    int t = threadIdx.x;
    int i = blockIdx.x * 256 + t;
    int v = (i < n) ? cnt[i] : 0;
    sh[t] = v; __syncthreads();
    for (int off = 1; off < 256; off <<= 1) {
        int add = (t >= off) ? sh[t - off] : 0;
        __syncthreads();
        sh[t] += add;
        __syncthreads();
    }
    if (i < n) rp[i] = sh[t] - v;
    if (t == 255) blkSum[blockIdx.x] = sh[255];
}

__global__ void scan_sums(const int* __restrict__ blkSum, int nb, int* __restrict__ blkOff,
                          int* __restrict__ rp, int n) {
    __shared__ int sh[256];
    int t = threadIdx.x;
    int v = (t < nb) ? blkSum[t] : 0;
    sh[t] = v; __syncthreads();
    for (int off = 1; off < 256; off <<= 1) {
        int add = (t >= off) ? sh[t - off] : 0;
        __syncthreads();
        sh[t] += add;
        __syncthreads();
    }
    blkOff[t] = sh[t] - v;
    if (t == 255) rp[n] = sh[255];
}

__global__ void scan_add(int* __restrict__ rp, int n, const int* __restrict__ blkOff) {
    int i = blockIdx.x * 256 + threadIdx.x;
    if (i < n) rp[i] += blkOff[blockIdx.x];
}

__global__ void fill_csr(const int* __restrict__ src, const int* __restrict__ dst, int E,
                         const int* __restrict__ rp, int* __restrict__ tmp,
                         const float* __restrict__ dinv, int* __restrict__ csrS,
                         float* __restrict__ csrW) {
    int e = blockIdx.x * blockDim.x + threadIdx.x;
    if (e >= E) return;
    int s = src[e], d = dst[e];
    int pos = rp[d] + atomicAdd(&tmp[d], 1);
    csrS[pos] = s;
    csrW[pos] = dinv[s] * dinv[d];
}

// ---------------- aggregation ----------------

// Column-split aggregation, F=256: 8 chunks of 32 cols; chunk = blockIdx&7 pins
// each chunk to one XCD under round-robin dispatch -> per-XCD gather working set
// = 30MB/8 = 3.75MB < 4MB L2. Two edges per wave-instr (parity = lane>>5).
__global__ void agg_cs256(const float* __restrict__ x, const int* __restrict__ rp,
                          const int* __restrict__ cs, const float* __restrict__ cw,
                          const float* __restrict__ dinv, float* __restrict__ z) {
    int b = blockIdx.x;
    int chunk = b & 7;
    int node = b >> 3;
    int t = threadIdx.x;  // 64
    int col = chunk * 32 + (t & 31);
    int par = t >> 5;     // 0,1
    float di = dinv[node];
    float acc = (par == 0) ? di * di * x[(size_t)node * 256 + col] : 0.f;
    int e0 = rp[node], e1 = rp[node + 1];
    for (int e = e0 + par; e < e1; e += 2)
        acc += cw[e] * x[(size_t)cs[e] * 256 + col];
    acc += __shfl_xor(acc, 32, 64);
    if (par == 0) z[(size_t)node * 256 + col] = acc;
}

// Column-split aggregation, F=128: 8 chunks of 16 cols; 4 edges per wave-instr.
__global__ void agg_cs128(const float* __restrict__ x, const int* __restrict__ rp,
                          const int* __restrict__ cs, const float* __restrict__ cw,
                          const float* __restrict__ dinv, float* __restrict__ z) {
    int b = blockIdx.x;
    int chunk = b & 7;
    int node = b >> 3;
    int t = threadIdx.x;  // 64
    int col = chunk * 16 + (t & 15);
    int par = t >> 4;     // 0..3
    float di = dinv[node];
    float acc = (par == 0) ? di * di * x[(size_t)node * 128 + col] : 0.f;
    int e0 = rp[node], e1 = rp[node + 1];
    for (int e = e0 + par; e < e1; e += 4)
        acc += cw[e] * x[(size_t)cs[e] * 128 + col];
    acc += __shfl_xor(acc, 32, 64);
    acc += __shfl_xor(acc, 16, 64);
    if (par == 0) z[(size_t)node * 128 + col] = acc;
}

// F = 256, float4: 64 threads per block (phase B: operand is L2-resident, keep simple)
__global__ void agg_f4(const float* __restrict__ x, const int* __restrict__ rp,
                       const int* __restrict__ cs, const float* __restrict__ cw,
                       const float* __restrict__ dinv, float* __restrict__ z) {
    int node = blockIdx.x;
    int t = threadIdx.x;  // 0..63
    const float4* x4 = (const float4*)x;
    float di = dinv[node];
    float w0 = di * di;
    float4 xv = x4[(size_t)node * 64 + t];
    float ax = w0 * xv.x, ay = w0 * xv.y, az = w0 * xv.z, aw = w0 * xv.w;
    int e0 = rp[node], e1 = rp[node + 1];
    for (int e = e0; e < e1; ++e) {
        int s = cs[e];
        float w = cw[e];
        float4 v = x4[(size_t)s * 64 + t];
        ax += w * v.x; ay += w * v.y; az += w * v.z; aw += w * v.w;
    }
    float4 o; o.x = ax; o.y = ay; o.z = az; o.w = aw;
    ((float4*)z)[(size_t)node * 64 + t] = o;
}

// small F (17), scalar
__global__ void agg_small(const float* __restrict__ x, const int* __restrict__ rp,
                          const int* __restrict__ cs, const float* __restrict__ cw,
                          const float* __restrict__ dinv, float* __restrict__ z, int F) {
    int node = blockIdx.x;
    int t = threadIdx.x;
    if (t >= F) return;
    float di = dinv[node];
    float acc = di * di * x[(size_t)node * F + t];
    int e0 = rp[node], e1 = rp[node + 1];
    for (int e = e0; e < e1; ++e) {
        acc += cw[e] * x[(size_t)cs[e] * F + t];
    }
    z[(size_t)node * F + t] = acc;
}

// ---------------- GEMM (M x K) @ (K x 256) + bias + BN (+ReLU) ----------------
// 64x64 tile, 256 threads, 4x4 microtile, BK=16

template <int K, bool RELU, bool ZEROEMPTY>
__global__ __launch_bounds__(256) void gemm_bn(
    const float* __restrict__ A, const float* __restrict__ W,
    const float* __restrict__ bias, const float* __restrict__ gam,
    const float* __restrict__ bet, const float* __restrict__ mu,
    const float* __restrict__ var, const int* __restrict__ cnt,
    float* __restrict__ out, int M) {
    __shared__ __align__(16) float As[16][64];
    __shared__ __align__(16) float Bs[16][64];
    int tid = threadIdx.x;
    int tm = tid >> 4, tn = tid & 15;
    int row0 = blockIdx.x * 64, col0 = blockIdx.y * 64;
    float acc[4][4] = {};
    int ar = tid >> 2;           // 0..63
    int ak = (tid & 3) * 4;      // 0,4,8,12
    int bk = tid >> 4;           // 0..15
    int bn = (tid & 15) * 4;     // 0..60

    for (int kk = 0; kk < K; kk += 16) {
        float4 av = make_float4(0.f, 0.f, 0.f, 0.f);
        int grow = row0 + ar;
        if (grow < M) av = *(const float4*)(A + (size_t)grow * K + kk + ak);
        As[ak + 0][ar] = av.x;
        As[ak + 1][ar] = av.y;
        As[ak + 2][ar] = av.z;
        As[ak + 3][ar] = av.w;
        float4 bv = *(const float4*)(W + (size_t)(kk + bk) * 256 + col0 + bn);
        *(float4*)&Bs[bk][bn] = bv;
        __syncthreads();
#pragma unroll
        for (int k = 0; k < 16; ++k) {
            float4 a = *(const float4*)&As[k][tm * 4];
            float4 b = *(const float4*)&Bs[k][tn * 4];
            acc[0][0] += a.x * b.x; acc[0][1] += a.x * b.y; acc[0][2] += a.x * b.z; acc[0][3] += a.x * b.w;
            acc[1][0] += a.y * b.x; acc[1][1] += a.y * b.y; acc[1][2] += a.y * b.z; acc[1][3] += a.y * b.w;
            acc[2][0] += a.z * b.x; acc[2][1] += a.z * b.y; acc[2][2] += a.z * b.z; acc[2][3] += a.z * b.w;
            acc[3][0] += a.w * b.x; acc[3][1] += a.w * b.y; acc[3][2] += a.w * b.z; acc[3][3] += a.w * b.w;
        }
        __syncthreads();
    }
    // epilogue: per-column BN params
    float bcol[4], scol[4], mcol[4], ecol[4];
#pragma unroll
    for (int j = 0; j < 4; ++j) {
        int col = col0 + tn * 4 + j;
        bcol[j] = bias[col];
        scol[j] = gam[col] * rsqrtf(var[col] + EPSc);
        mcol[j] = mu[col];
        ecol[j] = bet[col];
    }
#pragma unroll
    for (int i = 0; i < 4; ++i) {
        int row = row0 + tm * 4 + i;
        if (row >= M) continue;
        bool zero = false;
        if (ZEROEMPTY) zero = (cnt[row] == 0);
        float4 o;
        float r[4];
#pragma unroll
        for (int j = 0; j < 4; ++j) {
            float v = acc[i][j] + bcol[j];
            v = (v - mcol[j]) * scol[j] + ecol[j];
            if (RELU) v = fmaxf(v, 0.f);
            if (zero) v = 0.f;
            r[j] = v;
        }
        o.x = r[0]; o.y = r[1]; o.z = r[2]; o.w = r[3];
        *(float4*)(out + (size_t)row * 256 + col0 + tn * 4) = o;
    }
}

// K=17 GEMM: block per row, 256 threads
__global__ void gemm17_bn_relu(const float* __restrict__ A, const float* __restrict__ W,
                               const float* __restrict__ bias, const float* __restrict__ gam,
                               const float* __restrict__ bet, const float* __restrict__ mu,
                               const float* __restrict__ var, float* __restrict__ out) {
    int r = blockIdx.x, t = threadIdx.x;
    __shared__ float zr[17];
    if (t < 17) zr[t] = A[(size_t)r * 17 + t];
    __syncthreads();
    float acc = bias[t];
#pragma unroll
    for (int k = 0; k < 17; ++k) acc += zr[k] * W[k * 256 + t];
    float s = gam[t] * rsqrtf(var[t] + EPSc);
    acc = (acc - mu[t]) * s + bet[t];
    acc = fmaxf(acc, 0.f);
    out[(size_t)r * 256 + t] = acc;
}

// ---------------- pooling ----------------

// cluster starts from SORTED pool1
__global__ void seg_starts(const int* __restrict__ pool, int n, int nseg,
                           int* __restrict__ start) {
    int i = blockIdx.x * blockDim.x + threadIdx.x;
    if (i > n) return;
    if (i == 0) {
        for (int c = 0; c <= pool[0]; ++c) start[c] = 0;
    } else if (i == n) {
        for (int c = pool[n - 1] + 1; c <= nseg; ++c) start[c] = n;
    } else {
        int a = pool[i - 1], b = pool[i];
        for (int c = a + 1; c <= b; ++c) start[c] = i;
    }
}

// block per cluster: mean of z rows + cnt + bpool
__global__ void pool_mean(const float* __restrict__ z, const int* __restrict__ start,
                          const int* __restrict__ batch, float* __restrict__ p,
                          int* __restrict__ cnt_out, int* __restrict__ bpool) {
    int c = blockIdx.x, t = threadIdx.x;  // 64 threads
    int s = start[c], e = start[c + 1];
    int cnt = e - s;
    const float4* z4 = (const float4*)z;
    float ax = 0.f, ay = 0.f, az = 0.f, aw = 0.f;
    for (int i = s; i < e; ++i) {
        float4 v = z4[(size_t)i * 64 + t];
        ax += v.x; ay += v.y; az += v.z; aw += v.w;
    }
    float inv = 1.0f / (float)max(cnt, 1);
    float4 o; o.x = ax * inv; o.y = ay * inv; o.z = az * inv; o.w = aw * inv;
    ((float4*)p)[(size_t)c * 64 + t] = o;
    if (t == 0) {
        cnt_out[c] = cnt;
        int sb = 0;
        for (int i = s; i < e; ++i) sb += batch[i];
        bpool[c] = (int)rintf((float)sb * inv);  // exact integer -> round safe
    }
}

__global__ void pool_b_accum(const float* __restrict__ z, const int* __restrict__ bpool,
                             float* __restrict__ pb) {
    int c = blockIdx.x, t = threadIdx.x;  // 64 threads
    int b = bpool[c];
#pragma unroll
    for (int j = 0; j < 4; ++j)
        atomicAdd(&pb[b * 256 + t * 4 + j], z[(size_t)c * 256 + t * 4 + j]);
}

__global__ void cntB_accum(const int* __restrict__ bpool, int* __restrict__ cntB, int n) {
    int c = blockIdx.x * blockDim.x + threadIdx.x;
    if (c < n) atomicAdd(&cntB[bpool[c]], 1);
}

// ---------------- heads ----------------

// logits0 + softmax + write x0 to d_out + build xb = [x0 | x_pool1]
__global__ void head0(const float* __restrict__ xp, const float* __restrict__ linW,
                      const float* __restrict__ linb, const float* __restrict__ xpool1,
                      float* __restrict__ outp, float* __restrict__ xb) {
    int r = blockIdx.x, t = threadIdx.x;  // 64 threads
    __shared__ float xr[256];
    __shared__ float lg[16];
    __shared__ float ex[16];
#pragma unroll
    for (int j = 0; j < 4; ++j) xr[t + 64 * j] = xp[(size_t)r * 256 + t + 64 * j];
    __syncthreads();
    if (t < 16) {
        float acc = linb[t];
        for (int k = 0; k < 256; ++k) acc += xr[k] * linW[k * 16 + t];
        lg[t] = acc;
    }
    __syncthreads();
    if (t < 16) {
        float mx = lg[0];
#pragma unroll
        for (int c = 1; c < 16; ++c) mx = fmaxf(mx, lg[c]);
        ex[t] = expf(lg[t] - mx);
    }
    __syncthreads();
    if (t < 16) {
        float sum = 0.f;
#pragma unroll
        for (int c = 0; c < 16; ++c) sum += ex[c];
        float pv = ex[t] / sum;
        outp[(size_t)r * 16 + t] = pv;
        xb[(size_t)r * 17 + t] = pv;
    }
    if (t == 16) xb[(size_t)r * 17 + 16] = xpool1[r];
}

// final: mean(pb) -> layer2 GEMM+BN -> logits -> softmax -> d_out tail
__global__ void head1(const float* __restrict__ pb, const int* __restrict__ cntB,
                      const float* __restrict__ W, const float* __restrict__ bias,
                      const float* __restrict__ gam, const float* __restrict__ bet,
                      const float* __restrict__ mu, const float* __restrict__ var,
                      const float* __restrict__ linW, const float* __restrict__ linb,
                      float* __restrict__ outp) {
    int b = blockIdx.x, t = threadIdx.x;  // 256 threads
    __shared__ float pr[256];
    __shared__ float yr[256];
    __shared__ float lg[16];
    __shared__ float ex[16];
    int c = cntB[b];
    float inv = 1.0f / (float)max(c, 1);
    pr[t] = pb[b * 256 + t] * inv;
    __syncthreads();
    float acc = bias[t];
    for (int k = 0; k < 256; ++k) acc += pr[k] * W[k * 256 + t];
    float s = gam[t] * rsqrtf(var[t] + EPSc);
    acc = (acc - mu[t]) * s + bet[t];
    if (c == 0) acc = 0.f;
    yr[t] = acc;
    __syncthreads();
    if (t < 16) {
        float l = linb[t];
        for (int k = 0; k < 256; ++k) l += yr[k] * linW[k * 16 + t];
        lg[t] = l;
    }
    __syncthreads();
    if (t < 16) {
        float mx = lg[0];
#pragma unroll
        for (int cc = 1; cc < 16; ++cc) mx = fmaxf(mx, lg[cc]);
        ex[t] = expf(lg[t] - mx);
    }
    __syncthreads();
    if (t < 16) {
        float sum = 0.f;
#pragma unroll
        for (int cc = 0; cc < 16; ++cc) sum += ex[cc];
        outp[48000 + b * 16 + t] = ex[t] / sum;
    }
}

// ---------------- launch ----------------

extern "C" void kernel_launch(void* const* d_in, const int* in_sizes, int n_in,
                              void* d_out, int out_size, void* d_ws, size_t ws_size,
                              hipStream_t stream) {
    const float* x       = (const float*)d_in[0];
    const float* x_pool1 = (const float*)d_in[1];
    const float* W_in0   = (const float*)d_in[2];
    const float* W_h0    = (const float*)d_in[3];
    const float* b0      = (const float*)d_in[4];
    const float* g0      = (const float*)d_in[5];
    const float* be0     = (const float*)d_in[6];
    const float* m0      = (const float*)d_in[7];
    const float* v0      = (const float*)d_in[8];
    const float* W_in1   = (const float*)d_in[9];
    const float* W_h1    = (const float*)d_in[10];
    const float* b1      = (const float*)d_in[11];
    const float* g1      = (const float*)d_in[12];
    const float* be1     = (const float*)d_in[13];
    const float* m1      = (const float*)d_in[14];
    const float* v1      = (const float*)d_in[15];
    const float* linW0   = (const float*)d_in[16];
    const float* linb0   = (const float*)d_in[17];
    const float* linW1   = (const float*)d_in[18];
    const float* linb1   = (const float*)d_in[19];
    const int*   ei      = (const int*)d_in[20];
    const int*   batch   = (const int*)d_in[21];
    const int*   pool1   = (const int*)d_in[22];
    const int*   eip     = (const int*)d_in[23];
    float* outp = (float*)d_out;

    // carve workspace (256B-aligned)
    char* p = (char*)d_ws;
    auto carve = [&](size_t bytes) -> void* {
        void* r = (void*)p;
        p += (bytes + 255) & ~(size_t)255;
        return r;
    };
    int*   deg0   = (int*)  carve((size_t)N0c * 4);
    int*   tmp0   = (int*)  carve((size_t)N0c * 4);
    int*   rp0    = (int*)  carve((size_t)(N0c + 1) * 4);
    float* dinv0  = (float*)carve((size_t)N0c * 4);
    int*   blkSum = (int*)  carve(256 * 4);
    int*   blkOff = (int*)  carve(256 * 4);
    int*   csrS0  = (int*)  carve((size_t)E0c * 4);
    float* csrW0  = (float*)carve((size_t)E0c * 4);
    float* bufA   = (float*)carve((size_t)N0c * Hc * 4);
    float* bufB   = (float*)carve((size_t)N0c * Hc * 4);
    int*   start0 = (int*)  carve((size_t)(N1c + 1) * 4);
    int*   cnt0   = (int*)  carve((size_t)N1c * 4);
    float* pmean  = (float*)carve((size_t)N1c * Hc * 4);
    float* xp     = (float*)carve((size_t)N1c * Hc * 4);
    float* xb     = (float*)carve((size_t)N1c * 17 * 4);
    float* zb17   = (float*)carve((size_t)N1c * 17 * 4);
    int*   bpool  = (int*)  carve((size_t)N1c * 4);
    int*   deg1   = (int*)  carve((size_t)N1c * 4);
    int*   tmp1   = (int*)  carve((size_t)N1c * 4);
    int*   rp1    = (int*)  carve((size_t)(N1c + 1) * 4);
    float* dinv1  = (float*)carve((size_t)N1c * 4);
    int*   csrS1  = (int*)  carve((size_t)E1c * 4);
    float* csrW1  = (float*)carve((size_t)E1c * 4);
    float* zbb    = (float*)carve((size_t)N1c * Hc * 4);
    float* hbb    = (float*)carve((size_t)N1c * Hc * 4);
    float* pb     = (float*)carve((size_t)Bc * Hc * 4);
    int*   cntB   = (int*)  carve((size_t)Bc * 4);

    // zero-init accumulators (ws is poisoned every call)
    hipMemsetAsync(deg0, 0, (size_t)N0c * 4, stream);
    hipMemsetAsync(tmp0, 0, (size_t)N0c * 4, stream);
    hipMemsetAsync(deg1, 0, (size_t)N1c * 4, stream);
    hipMemsetAsync(tmp1, 0, (size_t)N1c * 4, stream);
    hipMemsetAsync(pb,   0, (size_t)Bc * Hc * 4, stream);
    hipMemsetAsync(cntB, 0, (size_t)Bc * 4, stream);

    const int* src0 = ei;
    const int* dst0 = ei + E0c;
    const int* src1 = eip;
    const int* dst1 = eip + E1c;

    // ---- graph 0 CSR ----
    count_deg<<<cdiv_i(E0c, 256), 256, 0, stream>>>(dst0, E0c, deg0);
    calc_dinv<<<cdiv_i(N0c, 256), 256, 0, stream>>>(deg0, dinv0, N0c);
    int nb0 = cdiv_i(N0c, 256);
    scan_block<<<nb0, 256, 0, stream>>>(deg0, N0c, rp0, blkSum);
    scan_sums<<<1, 256, 0, stream>>>(blkSum, nb0, blkOff, rp0, N0c);
    scan_add<<<nb0, 256, 0, stream>>>(rp0, N0c, blkOff);
    fill_csr<<<cdiv_i(E0c, 256), 256, 0, stream>>>(src0, dst0, E0c, rp0, tmp0, dinv0, csrS0, csrW0);

    // ---- phase A: 3 GCN layers on N0, aggregate-first ----
    agg_cs128<<<8 * N0c, 64, 0, stream>>>(x, rp0, csrS0, csrW0, dinv0, bufA);
    gemm_bn<128, true, false><<<dim3(cdiv_i(N0c, 64), 4), 256, 0, stream>>>(
        bufA, W_in0, b0, g0, be0, m0, v0, nullptr, bufB, N0c);
    agg_cs256<<<8 * N0c, 64, 0, stream>>>(bufB, rp0, csrS0, csrW0, dinv0, bufA);
    gemm_bn<256, true, false><<<dim3(cdiv_i(N0c, 64), 4), 256, 0, stream>>>(
        bufA, W_h0, b0 + Hc, g0 + Hc, be0 + Hc, m0 + Hc, v0 + Hc, nullptr, bufB, N0c);
    agg_cs256<<<8 * N0c, 64, 0, stream>>>(bufB, rp0, csrS0, csrW0, dinv0, bufA);

    // layer 2: pool BEFORE GEMM (affine reorder); zero empty clusters in epilogue
    seg_starts<<<cdiv_i(N0c + 1, 256), 256, 0, stream>>>(pool1, N0c, N1c, start0);
    pool_mean<<<N1c, 64, 0, stream>>>(bufA, start0, batch, pmean, cnt0, bpool);
    gemm_bn<256, false, true><<<dim3(cdiv_i(N1c, 64), 4), 256, 0, stream>>>(
        pmean, W_h0 + Hc * Hc, b0 + 2 * Hc, g0 + 2 * Hc, be0 + 2 * Hc, m0 + 2 * Hc,
        v0 + 2 * Hc, cnt0, xp, N1c);

    // head0: logits + softmax -> d_out[0:48000], xb = [x0 | x_pool1]
    head0<<<N1c, 64, 0, stream>>>(xp, linW0, linb0, x_pool1, outp, xb);

    // ---- graph 1 CSR ----
    count_deg<<<cdiv_i(E1c, 256), 256, 0, stream>>>(dst1, E1c, deg1);
    calc_dinv<<<cdiv_i(N1c, 256), 256, 0, stream>>>(deg1, dinv1, N1c);
    int nb1 = cdiv_i(N1c, 256);
    scan_block<<<nb1, 256, 0, stream>>>(deg1, N1c, rp1, blkSum);
    scan_sums<<<1, 256, 0, stream>>>(blkSum, nb1, blkOff, rp1, N1c);
    scan_add<<<nb1, 256, 0, stream>>>(rp1, N1c, blkOff);
    fill_csr<<<cdiv_i(E1c, 256), 256, 0, stream>>>(src1, dst1, E1c, rp1, tmp1, dinv1, csrS1, csrW1);

    // ---- phase B: 3 GCN layers on N1 ----
    agg_small<<<N1c, 64, 0, stream>>>(xb, rp1, csrS1, csrW1, dinv1, zb17, 17);
    gemm17_bn_relu<<<N1c, 256, 0, stream>>>(zb17, W_in1, b1, g1, be1, m1, v1, hbb);
    agg_f4<<<N1c, 64, 0, stream>>>(hbb, rp1, csrS1, csrW1, dinv1, zbb);
    gemm_bn<256, true, false><<<dim3(cdiv_i(N1c, 64), 4), 256, 0, stream>>>(
        zbb, W_h1, b1 + Hc, g1 + Hc, be1 + Hc, m1 + Hc, v1 + Hc, nullptr, hbb, N1c);
    agg_f4<<<N1c, 64, 0, stream>>>(hbb, rp1, csrS1, csrW1, dinv1, zbb);

    // layer 2: pool to B graphs BEFORE GEMM (bpool is NOT sorted -> atomics)
    pool_b_accum<<<N1c, 64, 0, stream>>>(zbb, bpool, pb);
    cntB_accum<<<cdiv_i(N1c, 256), 256, 0, stream>>>(bpool, cntB, N1c);

    // head1: layer2 GEMM+BN + logits + softmax -> d_out[48000:48256]
    head1<<<Bc, 256, 0, stream>>>(pb, cntB, W_h1 + Hc * Hc, b1 + 2 * Hc, g1 + 2 * Hc,
                                  be1 + 2 * Hc, m1 + 2 * Hc, v1 + 2 * Hc, linW1, linb1,
                                  outp);
}

// Round 3
// 791.443 us; speedup vs baseline: 1.5101x; 1.5101x over previous
//
#include <hip/hip_runtime.h>
#include <cstdint>
#include <cstddef>

// Problem constants
#define N0c 30000
#define F0c 128
#define Hc  256
#define Cc  16
#define N1c 3000
#define Bc  16
#define E0c 960000
#define E1c 48000
#define EPSc 1e-5f

static __host__ __device__ inline int cdiv_i(int a, int b) { return (a + b - 1) / b; }

// ---------------- graph preprocessing ----------------

__global__ void count_deg(const int* __restrict__ dst, int E, int* __restrict__ deg) {
    int e = blockIdx.x * blockDim.x + threadIdx.x;
    if (e < E) atomicAdd(&deg[dst[e]], 1);
}

__global__ void calc_dinv(const int* __restrict__ deg, float* __restrict__ dinv, int n) {
    int i = blockIdx.x * blockDim.x + threadIdx.x;
    if (i < n) dinv[i] = rsqrtf((float)(deg[i] + 1));  // +1 self loop, always > 0
}

// exclusive scan of cnt[n] -> rp[n] (+ rp[n]=total), 3-kernel multi-block scan (nb<=256)
__global__ void scan_block(const int* __restrict__ cnt, int n, int* __restrict__ rp,
                           int* __restrict__ blkSum) {
    __shared__ int sh[256];
    int t = threadIdx.x;
    int i = blockIdx.x * 256 + t;
    int v = (i < n) ? cnt[i] : 0;
    sh[t] = v; __syncthreads();
    for (int off = 1; off < 256; off <<= 1) {
        int add = (t >= off) ? sh[t - off] : 0;
        __syncthreads();
        sh[t] += add;
        __syncthreads();
    }
    if (i < n) rp[i] = sh[t] - v;
    if (t == 255) blkSum[blockIdx.x] = sh[255];
}

__global__ void scan_sums(const int* __restrict__ blkSum, int nb, int* __restrict__ blkOff,
                          int* __restrict__ rp, int n) {
    __shared__ int sh[256];
    int t = threadIdx.x;
    int v = (t < nb) ? blkSum[t] : 0;
    sh[t] = v; __syncthreads();
    for (int off = 1; off < 256; off <<= 1) {
        int add = (t >= off) ? sh[t - off] : 0;
        __syncthreads();
        sh[t] += add;
        __syncthreads();
    }
    blkOff[t] = sh[t] - v;
    if (t == 255) rp[n] = sh[255];
}

__global__ void scan_add(int* __restrict__ rp, int n, const int* __restrict__ blkOff) {
    int i = blockIdx.x * 256 + threadIdx.x;
    if (i < n) rp[i] += blkOff[blockIdx.x];
}

// packed CSR entry: {src, float_bits(weight)} -> one 8B load per edge
__global__ void fill_csr(const int* __restrict__ src, const int* __restrict__ dst, int E,
                         const int* __restrict__ rp, int* __restrict__ tmp,
                         const float* __restrict__ dinv, int2* __restrict__ csw) {
    int e = blockIdx.x * blockDim.x + threadIdx.x;
    if (e >= E) return;
    int s = src[e], d = dst[e];
    int pos = rp[d] + atomicAdd(&tmp[d], 1);
    int2 v;
    v.x = s;
    v.y = __float_as_int(dinv[s] * dinv[d]);
    csw[pos] = v;
}

// ---------------- aggregation ----------------

// Wide column-split aggregation.
// RS4 = row length in float4 units (64 for F=256, 32 for F=128).
// NCHUNK chunks of 32 cols; chunk = blockIdx & (NCHUNK-1) pins each chunk to a
// fixed XCD set (round-robin dispatch) -> per-XCD gather slice fits in 4MB L2.
// Lane layout: par = t>>3 picks one of 8 edges, cl = t&7 picks float4 in chunk.
// One x-load instruction = 8 edges x 128B = 1KB.
template <int RS4, int NCHUNK>
__global__ void agg_wide(const float* __restrict__ x, const int* __restrict__ rp,
                         const int2* __restrict__ csw, const float* __restrict__ dinv,
                         float* __restrict__ z) {
    int b = blockIdx.x;
    int chunk = b & (NCHUNK - 1);
    int node = b / NCHUNK;
    int t = threadIdx.x;      // 64
    int par = t >> 3;         // 0..7 edge slot
    int cl = t & 7;           // float4 lane within 32-col chunk
    int c4 = chunk * 8 + cl;  // float4 column index
    const float4* x4 = (const float4*)x;
    float4 a = make_float4(0.f, 0.f, 0.f, 0.f);
    if (par == 0) {  // self-loop term exactly once
        float di = dinv[node];
        float w0 = di * di;
        float4 xv = x4[(size_t)node * RS4 + c4];
        a.x = w0 * xv.x; a.y = w0 * xv.y; a.z = w0 * xv.z; a.w = w0 * xv.w;
    }
    int e0 = rp[node], e1 = rp[node + 1];
    for (int e = e0 + par; e < e1; e += 8) {
        int2 sw = csw[e];
        float w = __int_as_float(sw.y);
        float4 v = x4[(size_t)sw.x * RS4 + c4];
        a.x += w * v.x; a.y += w * v.y; a.z += w * v.z; a.w += w * v.w;
    }
#pragma unroll
    for (int m = 8; m < 64; m <<= 1) {
        a.x += __shfl_xor(a.x, m, 64);
        a.y += __shfl_xor(a.y, m, 64);
        a.z += __shfl_xor(a.z, m, 64);
        a.w += __shfl_xor(a.w, m, 64);
    }
    if (par == 0) ((float4*)z)[(size_t)node * RS4 + c4] = a;
}

// F = 256, float4: 64 threads per block (phase B: operand is small, keep simple)
__global__ void agg_f4(const float* __restrict__ x, const int* __restrict__ rp,
                       const int2* __restrict__ csw, const float* __restrict__ dinv,
                       float* __restrict__ z) {
    int node = blockIdx.x;
    int t = threadIdx.x;  // 0..63
    const float4* x4 = (const float4*)x;
    float di = dinv[node];
    float w0 = di * di;
    float4 xv = x4[(size_t)node * 64 + t];
    float ax = w0 * xv.x, ay = w0 * xv.y, az = w0 * xv.z, aw = w0 * xv.w;
    int e0 = rp[node], e1 = rp[node + 1];
    for (int e = e0; e < e1; ++e) {
        int2 sw = csw[e];
        float w = __int_as_float(sw.y);
        float4 v = x4[(size_t)sw.x * 64 + t];
        ax += w * v.x; ay += w * v.y; az += w * v.z; aw += w * v.w;
    }
    float4 o; o.x = ax; o.y = ay; o.z = az; o.w = aw;
    ((float4*)z)[(size_t)node * 64 + t] = o;
}

// small F (17), scalar
__global__ void agg_small(const float* __restrict__ x, const int* __restrict__ rp,
                          const int2* __restrict__ csw, const float* __restrict__ dinv,
                          float* __restrict__ z, int F) {
    int node = blockIdx.x;
    int t = threadIdx.x;
    if (t >= F) return;
    float di = dinv[node];
    float acc = di * di * x[(size_t)node * F + t];
    int e0 = rp[node], e1 = rp[node + 1];
    for (int e = e0; e < e1; ++e) {
        int2 sw = csw[e];
        acc += __int_as_float(sw.y) * x[(size_t)sw.x * F + t];
    }
    z[(size_t)node * F + t] = acc;
}

// ---------------- GEMM (M x K) @ (K x 256) + bias + BN (+ReLU) ----------------
// 64x64 tile, 256 threads, 4x4 microtile, BK=16

template <int K, bool RELU, bool ZEROEMPTY>
__global__ __launch_bounds__(256) void gemm_bn(
    const float* __restrict__ A, const float* __restrict__ W,
    const float* __restrict__ bias, const float* __restrict__ gam,
    const float* __restrict__ bet, const float* __restrict__ mu,
    const float* __restrict__ var, const int* __restrict__ cnt,
    float* __restrict__ out, int M) {
    __shared__ __align__(16) float As[16][64];
    __shared__ __align__(16) float Bs[16][64];
    int tid = threadIdx.x;
    int tm = tid >> 4, tn = tid & 15;
    int row0 = blockIdx.x * 64, col0 = blockIdx.y * 64;
    float acc[4][4] = {};
    int ar = tid >> 2;           // 0..63
    int ak = (tid & 3) * 4;      // 0,4,8,12
    int bk = tid >> 4;           // 0..15
    int bn = (tid & 15) * 4;     // 0..60

    for (int kk = 0; kk < K; kk += 16) {
        float4 av = make_float4(0.f, 0.f, 0.f, 0.f);
        int grow = row0 + ar;
        if (grow < M) av = *(const float4*)(A + (size_t)grow * K + kk + ak);
        As[ak + 0][ar] = av.x;
        As[ak + 1][ar] = av.y;
        As[ak + 2][ar] = av.z;
        As[ak + 3][ar] = av.w;
        float4 bv = *(const float4*)(W + (size_t)(kk + bk) * 256 + col0 + bn);
        *(float4*)&Bs[bk][bn] = bv;
        __syncthreads();
#pragma unroll
        for (int k = 0; k < 16; ++k) {
            float4 a = *(const float4*)&As[k][tm * 4];
            float4 b = *(const float4*)&Bs[k][tn * 4];
            acc[0][0] += a.x * b.x; acc[0][1] += a.x * b.y; acc[0][2] += a.x * b.z; acc[0][3] += a.x * b.w;
            acc[1][0] += a.y * b.x; acc[1][1] += a.y * b.y; acc[1][2] += a.y * b.z; acc[1][3] += a.y * b.w;
            acc[2][0] += a.z * b.x; acc[2][1] += a.z * b.y; acc[2][2] += a.z * b.z; acc[2][3] += a.z * b.w;
            acc[3][0] += a.w * b.x; acc[3][1] += a.w * b.y; acc[3][2] += a.w * b.z; acc[3][3] += a.w * b.w;
        }
        __syncthreads();
    }
    // epilogue: per-column BN params
    float bcol[4], scol[4], mcol[4], ecol[4];
#pragma unroll
    for (int j = 0; j < 4; ++j) {
        int col = col0 + tn * 4 + j;
        bcol[j] = bias[col];
        scol[j] = gam[col] * rsqrtf(var[col] + EPSc);
        mcol[j] = mu[col];
        ecol[j] = bet[col];
    }
#pragma unroll
    for (int i = 0; i < 4; ++i) {
        int row = row0 + tm * 4 + i;
        if (row >= M) continue;
        bool zero = false;
        if (ZEROEMPTY) zero = (cnt[row] == 0);
        float4 o;
        float r[4];
#pragma unroll
        for (int j = 0; j < 4; ++j) {
            float v = acc[i][j] + bcol[j];
            v = (v - mcol[j]) * scol[j] + ecol[j];
            if (RELU) v = fmaxf(v, 0.f);
            if (zero) v = 0.f;
            r[j] = v;
        }
        o.x = r[0]; o.y = r[1]; o.z = r[2]; o.w = r[3];
        *(float4*)(out + (size_t)row * 256 + col0 + tn * 4) = o;
    }
}

// K=17 GEMM: block per row, 256 threads
__global__ void gemm17_bn_relu(const float* __restrict__ A, const float* __restrict__ W,
                               const float* __restrict__ bias, const float* __restrict__ gam,
                               const float* __restrict__ bet, const float* __restrict__ mu,
                               const float* __restrict__ var, float* __restrict__ out) {
    int r = blockIdx.x, t = threadIdx.x;
    __shared__ float zr[17];
    if (t < 17) zr[t] = A[(size_t)r * 17 + t];
    __syncthreads();
    float acc = bias[t];
#pragma unroll
    for (int k = 0; k < 17; ++k) acc += zr[k] * W[k * 256 + t];
    float s = gam[t] * rsqrtf(var[t] + EPSc);
    acc = (acc - mu[t]) * s + bet[t];
    acc = fmaxf(acc, 0.f);
    out[(size_t)r * 256 + t] = acc;
}

// ---------------- pooling ----------------

// cluster starts from SORTED pool1
__global__ void seg_starts(const int* __restrict__ pool, int n, int nseg,
                           int* __restrict__ start) {
    int i = blockIdx.x * blockDim.x + threadIdx.x;
    if (i > n) return;
    if (i == 0) {
        for (int c = 0; c <= pool[0]; ++c) start[c] = 0;
    } else if (i == n) {
        for (int c = pool[n - 1] + 1; c <= nseg; ++c) start[c] = n;
    } else {
        int a = pool[i - 1], b = pool[i];
        for (int c = a + 1; c <= b; ++c) start[c] = i;
    }
}

// block per cluster: mean of z rows + cnt + bpool
__global__ void pool_mean(const float* __restrict__ z, const int* __restrict__ start,
                          const int* __restrict__ batch, float* __restrict__ p,
                          int* __restrict__ cnt_out, int* __restrict__ bpool) {
    int c = blockIdx.x, t = threadIdx.x;  // 64 threads
    int s = start[c], e = start[c + 1];
    int cnt = e - s;
    const float4* z4 = (const float4*)z;
    float ax = 0.f, ay = 0.f, az = 0.f, aw = 0.f;
    for (int i = s; i < e; ++i) {
        float4 v = z4[(size_t)i * 64 + t];
        ax += v.x; ay += v.y; az += v.z; aw += v.w;
    }
    float inv = 1.0f / (float)max(cnt, 1);
    float4 o; o.x = ax * inv; o.y = ay * inv; o.z = az * inv; o.w = aw * inv;
    ((float4*)p)[(size_t)c * 64 + t] = o;
    if (t == 0) {
        cnt_out[c] = cnt;
        int sb = 0;
        for (int i = s; i < e; ++i) sb += batch[i];
        bpool[c] = (int)rintf((float)sb * inv);  // exact integer -> round safe
    }
}

__global__ void pool_b_accum(const float* __restrict__ z, const int* __restrict__ bpool,
                             float* __restrict__ pb) {
    int c = blockIdx.x, t = threadIdx.x;  // 64 threads
    int b = bpool[c];
#pragma unroll
    for (int j = 0; j < 4; ++j)
        atomicAdd(&pb[b * 256 + t * 4 + j], z[(size_t)c * 256 + t * 4 + j]);
}

__global__ void cntB_accum(const int* __restrict__ bpool, int* __restrict__ cntB, int n) {
    int c = blockIdx.x * blockDim.x + threadIdx.x;
    if (c < n) atomicAdd(&cntB[bpool[c]], 1);
}

// ---------------- heads ----------------

// logits0 + softmax + write x0 to d_out + build xb = [x0 | x_pool1]
__global__ void head0(const float* __restrict__ xp, const float* __restrict__ linW,
                      const float* __restrict__ linb, const float* __restrict__ xpool1,
                      float* __restrict__ outp, float* __restrict__ xb) {
    int r = blockIdx.x, t = threadIdx.x;  // 64 threads
    __shared__ float xr[256];
    __shared__ float lg[16];
    __shared__ float ex[16];
#pragma unroll
    for (int j = 0; j < 4; ++j) xr[t + 64 * j] = xp[(size_t)r * 256 + t + 64 * j];
    __syncthreads();
    if (t < 16) {
        float acc = linb[t];
        for (int k = 0; k < 256; ++k) acc += xr[k] * linW[k * 16 + t];
        lg[t] = acc;
    }
    __syncthreads();
    if (t < 16) {
        float mx = lg[0];
#pragma unroll
        for (int c = 1; c < 16; ++c) mx = fmaxf(mx, lg[c]);
        ex[t] = expf(lg[t] - mx);
    }
    __syncthreads();
    if (t < 16) {
        float sum = 0.f;
#pragma unroll
        for (int c = 0; c < 16; ++c) sum += ex[c];
        float pv = ex[t] / sum;
        outp[(size_t)r * 16 + t] = pv;
        xb[(size_t)r * 17 + t] = pv;
    }
    if (t == 16) xb[(size_t)r * 17 + 16] = xpool1[r];
}

// final: mean(pb) -> layer2 GEMM+BN -> logits -> softmax -> d_out tail
__global__ void head1(const float* __restrict__ pb, const int* __restrict__ cntB,
                      const float* __restrict__ W, const float* __restrict__ bias,
                      const float* __restrict__ gam, const float* __restrict__ bet,
                      const float* __restrict__ mu, const float* __restrict__ var,
                      const float* __restrict__ linW, const float* __restrict__ linb,
                      float* __restrict__ outp) {
    int b = blockIdx.x, t = threadIdx.x;  // 256 threads
    __shared__ float pr[256];
    __shared__ float yr[256];
    __shared__ float lg[16];
    __shared__ float ex[16];
    int c = cntB[b];
    float inv = 1.0f / (float)max(c, 1);
    pr[t] = pb[b * 256 + t] * inv;
    __syncthreads();
    float acc = bias[t];
    for (int k = 0; k < 256; ++k) acc += pr[k] * W[k * 256 + t];
    float s = gam[t] * rsqrtf(var[t] + EPSc);
    acc = (acc - mu[t]) * s + bet[t];
    if (c == 0) acc = 0.f;
    yr[t] = acc;
    __syncthreads();
    if (t < 16) {
        float l = linb[t];
        for (int k = 0; k < 256; ++k) l += yr[k] * linW[k * 16 + t];
        lg[t] = l;
    }
    __syncthreads();
    if (t < 16) {
        float mx = lg[0];
#pragma unroll
        for (int cc = 1; cc < 16; ++cc) mx = fmaxf(mx, lg[cc]);
        ex[t] = expf(lg[t] - mx);
    }
    __syncthreads();
    if (t < 16) {
        float sum = 0.f;
#pragma unroll
        for (int cc = 0; cc < 16; ++cc) sum += ex[cc];
        outp[48000 + b * 16 + t] = ex[t] / sum;
    }
}

// ---------------- launch ----------------

extern "C" void kernel_launch(void* const* d_in, const int* in_sizes, int n_in,
                              void* d_out, int out_size, void* d_ws, size_t ws_size,
                              hipStream_t stream) {
    const float* x       = (const float*)d_in[0];
    const float* x_pool1 = (const float*)d_in[1];
    const float* W_in0   = (const float*)d_in[2];
    const float* W_h0    = (const float*)d_in[3];
    const float* b0      = (const float*)d_in[4];
    const float* g0      = (const float*)d_in[5];
    const float* be0     = (const float*)d_in[6];
    const float* m0      = (const float*)d_in[7];
    const float* v0      = (const float*)d_in[8];
    const float* W_in1   = (const float*)d_in[9];
    const float* W_h1    = (const float*)d_in[10];
    const float* b1      = (const float*)d_in[11];
    const float* g1      = (const float*)d_in[12];
    const float* be1     = (const float*)d_in[13];
    const float* m1      = (const float*)d_in[14];
    const float* v1      = (const float*)d_in[15];
    const float* linW0   = (const float*)d_in[16];
    const float* linb0   = (const float*)d_in[17];
    const float* linW1   = (const float*)d_in[18];
    const float* linb1   = (const float*)d_in[19];
    const int*   ei      = (const int*)d_in[20];
    const int*   batch   = (const int*)d_in[21];
    const int*   pool1   = (const int*)d_in[22];
    const int*   eip     = (const int*)d_in[23];
    float* outp = (float*)d_out;

    // carve workspace (256B-aligned)
    char* p = (char*)d_ws;
    auto carve = [&](size_t bytes) -> void* {
        void* r = (void*)p;
        p += (bytes + 255) & ~(size_t)255;
        return r;
    };
    int*   deg0   = (int*)  carve((size_t)N0c * 4);
    int*   tmp0   = (int*)  carve((size_t)N0c * 4);
    int*   rp0    = (int*)  carve((size_t)(N0c + 1) * 4);
    float* dinv0  = (float*)carve((size_t)N0c * 4);
    int*   blkSum = (int*)  carve(256 * 4);
    int*   blkOff = (int*)  carve(256 * 4);
    int2*  csw0   = (int2*) carve((size_t)E0c * 8);
    float* bufA   = (float*)carve((size_t)N0c * Hc * 4);
    float* bufB   = (float*)carve((size_t)N0c * Hc * 4);
    int*   start0 = (int*)  carve((size_t)(N1c + 1) * 4);
    int*   cnt0   = (int*)  carve((size_t)N1c * 4);
    float* pmean  = (float*)carve((size_t)N1c * Hc * 4);
    float* xp     = (float*)carve((size_t)N1c * Hc * 4);
    float* xb     = (float*)carve((size_t)N1c * 17 * 4);
    float* zb17   = (float*)carve((size_t)N1c * 17 * 4);
    int*   bpool  = (int*)  carve((size_t)N1c * 4);
    int*   deg1   = (int*)  carve((size_t)N1c * 4);
    int*   tmp1   = (int*)  carve((size_t)N1c * 4);
    int*   rp1    = (int*)  carve((size_t)(N1c + 1) * 4);
    float* dinv1  = (float*)carve((size_t)N1c * 4);
    int2*  csw1   = (int2*) carve((size_t)E1c * 8);
    float* zbb    = (float*)carve((size_t)N1c * Hc * 4);
    float* hbb    = (float*)carve((size_t)N1c * Hc * 4);
    float* pb     = (float*)carve((size_t)Bc * Hc * 4);
    int*   cntB   = (int*)  carve((size_t)Bc * 4);

    // zero-init accumulators (ws is poisoned every call)
    hipMemsetAsync(deg0, 0, (size_t)N0c * 4, stream);
    hipMemsetAsync(tmp0, 0, (size_t)N0c * 4, stream);
    hipMemsetAsync(deg1, 0, (size_t)N1c * 4, stream);
    hipMemsetAsync(tmp1, 0, (size_t)N1c * 4, stream);
    hipMemsetAsync(pb,   0, (size_t)Bc * Hc * 4, stream);
    hipMemsetAsync(cntB, 0, (size_t)Bc * 4, stream);

    const int* src0 = ei;
    const int* dst0 = ei + E0c;
    const int* src1 = eip;
    const int* dst1 = eip + E1c;

    // ---- graph 0 CSR ----
    count_deg<<<cdiv_i(E0c, 256), 256, 0, stream>>>(dst0, E0c, deg0);
    calc_dinv<<<cdiv_i(N0c, 256), 256, 0, stream>>>(deg0, dinv0, N0c);
    int nb0 = cdiv_i(N0c, 256);
    scan_block<<<nb0, 256, 0, stream>>>(deg0, N0c, rp0, blkSum);
    scan_sums<<<1, 256, 0, stream>>>(blkSum, nb0, blkOff, rp0, N0c);
    scan_add<<<nb0, 256, 0, stream>>>(rp0, N0c, blkOff);
    fill_csr<<<cdiv_i(E0c, 256), 256, 0, stream>>>(src0, dst0, E0c, rp0, tmp0, dinv0, csw0);

    // ---- phase A: 3 GCN layers on N0, aggregate-first ----
    agg_wide<32, 4><<<4 * N0c, 64, 0, stream>>>(x, rp0, csw0, dinv0, bufA);
    gemm_bn<128, true, false><<<dim3(cdiv_i(N0c, 64), 4), 256, 0, stream>>>(
        bufA, W_in0, b0, g0, be0, m0, v0, nullptr, bufB, N0c);
    agg_wide<64, 8><<<8 * N0c, 64, 0, stream>>>(bufB, rp0, csw0, dinv0, bufA);
    gemm_bn<256, true, false><<<dim3(cdiv_i(N0c, 64), 4), 256, 0, stream>>>(
        bufA, W_h0, b0 + Hc, g0 + Hc, be0 + Hc, m0 + Hc, v0 + Hc, nullptr, bufB, N0c);
    agg_wide<64, 8><<<8 * N0c, 64, 0, stream>>>(bufB, rp0, csw0, dinv0, bufA);

    // layer 2: pool BEFORE GEMM (affine reorder); zero empty clusters in epilogue
    seg_starts<<<cdiv_i(N0c + 1, 256), 256, 0, stream>>>(pool1, N0c, N1c, start0);
    pool_mean<<<N1c, 64, 0, stream>>>(bufA, start0, batch, pmean, cnt0, bpool);
    gemm_bn<256, false, true><<<dim3(cdiv_i(N1c, 64), 4), 256, 0, stream>>>(
        pmean, W_h0 + Hc * Hc, b0 + 2 * Hc, g0 + 2 * Hc, be0 + 2 * Hc, m0 + 2 * Hc,
        v0 + 2 * Hc, cnt0, xp, N1c);

    // head0: logits + softmax -> d_out[0:48000], xb = [x0 | x_pool1]
    head0<<<N1c, 64, 0, stream>>>(xp, linW0, linb0, x_pool1, outp, xb);

    // ---- graph 1 CSR ----
    count_deg<<<cdiv_i(E1c, 256), 256, 0, stream>>>(dst1, E1c, deg1);
    calc_dinv<<<cdiv_i(N1c, 256), 256, 0, stream>>>(deg1, dinv1, N1c);
    int nb1 = cdiv_i(N1c, 256);
    scan_block<<<nb1, 256, 0, stream>>>(deg1, N1c, rp1, blkSum);
    scan_sums<<<1, 256, 0, stream>>>(blkSum, nb1, blkOff, rp1, N1c);
    scan_add<<<nb1, 256, 0, stream>>>(rp1, N1c, blkOff);
    fill_csr<<<cdiv_i(E1c, 256), 256, 0, stream>>>(src1, dst1, E1c, rp1, tmp1, dinv1, csw1);

    // ---- phase B: 3 GCN layers on N1 ----
    agg_small<<<N1c, 64, 0, stream>>>(xb, rp1, csw1, dinv1, zb17, 17);
    gemm17_bn_relu<<<N1c, 256, 0, stream>>>(zb17, W_in1, b1, g1, be1, m1, v1, hbb);
    agg_f4<<<N1c, 64, 0, stream>>>(hbb, rp1, csw1, dinv1, zbb);
    gemm_bn<256, true, false><<<dim3(cdiv_i(N1c, 64), 4), 256, 0, stream>>>(
        zbb, W_h1, b1 + Hc, g1 + Hc, be1 + Hc, m1 + Hc, v1 + Hc, nullptr, hbb, N1c);
    agg_f4<<<N1c, 64, 0, stream>>>(hbb, rp1, csw1, dinv1, zbb);

    // layer 2: pool to B graphs BEFORE GEMM (bpool is NOT sorted -> atomics)
    pool_b_accum<<<N1c, 64, 0, stream>>>(zbb, bpool, pb);
    cntB_accum<<<cdiv_i(N1c, 256), 256, 0, stream>>>(bpool, cntB, N1c);

    // head1: layer2 GEMM+BN + logits + softmax -> d_out[48000:48256]
    head1<<<Bc, 256, 0, stream>>>(pb, cntB, W_h1 + Hc * Hc, b1 + 2 * Hc, g1 + 2 * Hc,
                                  be1 + 2 * Hc, m1 + 2 * Hc, v1 + 2 * Hc, linW1, linb1,
                                  outp);
}

// Round 4
// 764.881 us; speedup vs baseline: 1.5625x; 1.0347x over previous
//
#include <hip/hip_runtime.h>
#include <cstdint>
#include <cstddef>

// Problem constants
#define N0c 30000
#define F0c 128
#define Hc  256
#define Cc  16
#define N1c 3000
#define Bc  16
#define E0c 960000
#define E1c 48000
#define EPSc 1e-5f

static __host__ __device__ inline int cdiv_i(int a, int b) { return (a + b - 1) / b; }

// ---------------- graph preprocessing ----------------

__global__ void count_deg(const int* __restrict__ dst, int E, int* __restrict__ deg) {
    int e = blockIdx.x * blockDim.x + threadIdx.x;
    if (e < E) atomicAdd(&deg[dst[e]], 1);
}

__global__ void calc_dinv(const int* __restrict__ deg, float* __restrict__ dinv, int n) {
    int i = blockIdx.x * blockDim.x + threadIdx.x;
    if (i < n) dinv[i] = rsqrtf((float)(deg[i] + 1));  // +1 self loop, always > 0
}

// exclusive scan of cnt[n] -> rp[n] (+ rp[n]=total), 3-kernel multi-block scan (nb<=256)
__global__ void scan_block(const int* __restrict__ cnt, int n, int* __restrict__ rp,
                           int* __restrict__ blkSum) {
    __shared__ int sh[256];
    int t = threadIdx.x;
    int i = blockIdx.x * 256 + t;
    int v = (i < n) ? cnt[i] : 0;
    sh[t] = v; __syncthreads();
    for (int off = 1; off < 256; off <<= 1) {
        int add = (t >= off) ? sh[t - off] : 0;
        __syncthreads();
        sh[t] += add;
        __syncthreads();
    }
    if (i < n) rp[i] = sh[t] - v;
    if (t == 255) blkSum[blockIdx.x] = sh[255];
}

__global__ void scan_sums(const int* __restrict__ blkSum, int nb, int* __restrict__ blkOff,
                          int* __restrict__ rp, int n) {
    __shared__ int sh[256];
    int t = threadIdx.x;
    int v = (t < nb) ? blkSum[t] : 0;
    sh[t] = v; __syncthreads();
    for (int off = 1; off < 256; off <<= 1) {
        int add = (t >= off) ? sh[t - off] : 0;
        __syncthreads();
        sh[t] += add;
        __syncthreads();
    }
    blkOff[t] = sh[t] - v;
    if (t == 255) rp[n] = sh[255];
}

__global__ void scan_add(int* __restrict__ rp, int n, const int* __restrict__ blkOff) {
    int i = blockIdx.x * 256 + threadIdx.x;
    if (i < n) rp[i] += blkOff[blockIdx.x];
}

// packed CSR entry: {src, float_bits(weight)} -> one 8B load per edge
__global__ void fill_csr(const int* __restrict__ src, const int* __restrict__ dst, int E,
                         const int* __restrict__ rp, int* __restrict__ tmp,
                         const float* __restrict__ dinv, int2* __restrict__ csw) {
    int e = blockIdx.x * blockDim.x + threadIdx.x;
    if (e >= E) return;
    int s = src[e], d = dst[e];
    int pos = rp[d] + atomicAdd(&tmp[d], 1);
    int2 v;
    v.x = s;
    v.y = __float_as_int(dinv[s] * dinv[d]);
    csw[pos] = v;
}

// ---------------- aggregation ----------------

// Wide column-split aggregation, software-pipelined.
// RS4 = row length in float4 units (64 for F=256, 32 for F=128).
// NCHUNK chunks of 32 cols; chunk = blockIdx & (NCHUNK-1) pins each chunk to a
// fixed XCD set (round-robin dispatch) -> per-XCD gather slice fits in 4MB L2.
// Block = 256 threads = 4 waves; each wave handles one node (cuts dispatch 4x).
// Within a wave: lane = par*8+cl; par picks edge slot, cl picks float4 in chunk.
// Edge metadata is batch-loaded 64-edges-per-instruction into registers, then
// distributed via __shfl -> the 8 gathers of the unrolled inner loop are
// address-independent and stay in flight together (breaks the latency chain).
template <int RS4, int NCHUNK>
__global__ __launch_bounds__(256) void agg_wide(
    const float* __restrict__ x, const int* __restrict__ rp,
    const int2* __restrict__ csw, const float* __restrict__ dinv,
    float* __restrict__ z, int N) {
    int b = blockIdx.x;
    int chunk = b & (NCHUNK - 1);
    int wave = threadIdx.x >> 6;
    int node = (b / NCHUNK) * 4 + wave;
    if (node >= N) return;
    int lane = threadIdx.x & 63;
    int par = lane >> 3;      // 0..7 edge slot
    int cl = lane & 7;        // float4 lane within 32-col chunk
    int c4 = chunk * 8 + cl;  // float4 column index
    const float4* x4 = (const float4*)x;
    float4 a = make_float4(0.f, 0.f, 0.f, 0.f);
    if (par == 0) {  // self-loop term exactly once
        float di = dinv[node];
        float w0 = di * di;
        float4 xv = x4[(size_t)node * RS4 + c4];
        a.x = w0 * xv.x; a.y = w0 * xv.y; a.z = w0 * xv.z; a.w = w0 * xv.w;
    }
    int e0 = rp[node], e1 = rp[node + 1];
    for (int base = e0; base < e1; base += 64) {
        int avail = e1 - base;               // may exceed 64
        int2 my = make_int2(0, 0);
        if (lane < avail) my = csw[base + lane];  // 64 edges in ONE load
        int cnt = avail < 64 ? avail : 64;
#pragma unroll
        for (int i = 0; i < 8; ++i) {
            int idx = i * 8 + par;
            int sx = __shfl(my.x, idx, 64);
            float w = __int_as_float(__shfl(my.y, idx, 64));
            if (idx < cnt) {
                float4 v = x4[(size_t)sx * RS4 + c4];
                a.x += w * v.x; a.y += w * v.y; a.z += w * v.z; a.w += w * v.w;
            }
        }
    }
#pragma unroll
    for (int m = 8; m < 64; m <<= 1) {
        a.x += __shfl_xor(a.x, m, 64);
        a.y += __shfl_xor(a.y, m, 64);
        a.z += __shfl_xor(a.z, m, 64);
        a.w += __shfl_xor(a.w, m, 64);
    }
    if (par == 0) ((float4*)z)[(size_t)node * RS4 + c4] = a;
}

// small F (17), scalar
__global__ void agg_small(const float* __restrict__ x, const int* __restrict__ rp,
                          const int2* __restrict__ csw, const float* __restrict__ dinv,
                          float* __restrict__ z, int F) {
    int node = blockIdx.x;
    int t = threadIdx.x;
    if (t >= F) return;
    float di = dinv[node];
    float acc = di * di * x[(size_t)node * F + t];
    int e0 = rp[node], e1 = rp[node + 1];
    for (int e = e0; e < e1; ++e) {
        int2 sw = csw[e];
        acc += __int_as_float(sw.y) * x[(size_t)sw.x * F + t];
    }
    z[(size_t)node * F + t] = acc;
}

// ---------------- GEMM (M x K) @ (K x 256) + bias + BN (+ReLU) ----------------
// 64x64 tile, 256 threads, 4x4 microtile, BK=16

template <int K, bool RELU, bool ZEROEMPTY>
__global__ __launch_bounds__(256) void gemm_bn(
    const float* __restrict__ A, const float* __restrict__ W,
    const float* __restrict__ bias, const float* __restrict__ gam,
    const float* __restrict__ bet, const float* __restrict__ mu,
    const float* __restrict__ var, const int* __restrict__ cnt,
    float* __restrict__ out, int M) {
    __shared__ __align__(16) float As[16][64];
    __shared__ __align__(16) float Bs[16][64];
    int tid = threadIdx.x;
    int tm = tid >> 4, tn = tid & 15;
    int row0 = blockIdx.x * 64, col0 = blockIdx.y * 64;
    float acc[4][4] = {};
    int ar = tid >> 2;           // 0..63
    int ak = (tid & 3) * 4;      // 0,4,8,12
    int bk = tid >> 4;           // 0..15
    int bn = (tid & 15) * 4;     // 0..60

    for (int kk = 0; kk < K; kk += 16) {
        float4 av = make_float4(0.f, 0.f, 0.f, 0.f);
        int grow = row0 + ar;
        if (grow < M) av = *(const float4*)(A + (size_t)grow * K + kk + ak);
        As[ak + 0][ar] = av.x;
        As[ak + 1][ar] = av.y;
        As[ak + 2][ar] = av.z;
        As[ak + 3][ar] = av.w;
        float4 bv = *(const float4*)(W + (size_t)(kk + bk) * 256 + col0 + bn);
        *(float4*)&Bs[bk][bn] = bv;
        __syncthreads();
#pragma unroll
        for (int k = 0; k < 16; ++k) {
            float4 a = *(const float4*)&As[k][tm * 4];
            float4 b = *(const float4*)&Bs[k][tn * 4];
            acc[0][0] += a.x * b.x; acc[0][1] += a.x * b.y; acc[0][2] += a.x * b.z; acc[0][3] += a.x * b.w;
            acc[1][0] += a.y * b.x; acc[1][1] += a.y * b.y; acc[1][2] += a.y * b.z; acc[1][3] += a.y * b.w;
            acc[2][0] += a.z * b.x; acc[2][1] += a.z * b.y; acc[2][2] += a.z * b.z; acc[2][3] += a.z * b.w;
            acc[3][0] += a.w * b.x; acc[3][1] += a.w * b.y; acc[3][2] += a.w * b.z; acc[3][3] += a.w * b.w;
        }
        __syncthreads();
    }
    // epilogue: per-column BN params
    float bcol[4], scol[4], mcol[4], ecol[4];
#pragma unroll
    for (int j = 0; j < 4; ++j) {
        int col = col0 + tn * 4 + j;
        bcol[j] = bias[col];
        scol[j] = gam[col] * rsqrtf(var[col] + EPSc);
        mcol[j] = mu[col];
        ecol[j] = bet[col];
    }
#pragma unroll
    for (int i = 0; i < 4; ++i) {
        int row = row0 + tm * 4 + i;
        if (row >= M) continue;
        bool zero = false;
        if (ZEROEMPTY) zero = (cnt[row] == 0);
        float4 o;
        float r[4];
#pragma unroll
        for (int j = 0; j < 4; ++j) {
            float v = acc[i][j] + bcol[j];
            v = (v - mcol[j]) * scol[j] + ecol[j];
            if (RELU) v = fmaxf(v, 0.f);
            if (zero) v = 0.f;
            r[j] = v;
        }
        o.x = r[0]; o.y = r[1]; o.z = r[2]; o.w = r[3];
        *(float4*)(out + (size_t)row * 256 + col0 + tn * 4) = o;
    }
}

// K=17 GEMM: block per row, 256 threads
__global__ void gemm17_bn_relu(const float* __restrict__ A, const float* __restrict__ W,
                               const float* __restrict__ bias, const float* __restrict__ gam,
                               const float* __restrict__ bet, const float* __restrict__ mu,
                               const float* __restrict__ var, float* __restrict__ out) {
    int r = blockIdx.x, t = threadIdx.x;
    __shared__ float zr[17];
    if (t < 17) zr[t] = A[(size_t)r * 17 + t];
    __syncthreads();
    float acc = bias[t];
#pragma unroll
    for (int k = 0; k < 17; ++k) acc += zr[k] * W[k * 256 + t];
    float s = gam[t] * rsqrtf(var[t] + EPSc);
    acc = (acc - mu[t]) * s + bet[t];
    acc = fmaxf(acc, 0.f);
    out[(size_t)r * 256 + t] = acc;
}

// ---------------- pooling ----------------

// cluster starts from SORTED pool1
__global__ void seg_starts(const int* __restrict__ pool, int n, int nseg,
                           int* __restrict__ start) {
    int i = blockIdx.x * blockDim.x + threadIdx.x;
    if (i > n) return;
    if (i == 0) {
        for (int c = 0; c <= pool[0]; ++c) start[c] = 0;
    } else if (i == n) {
        for (int c = pool[n - 1] + 1; c <= nseg; ++c) start[c] = n;
    } else {
        int a = pool[i - 1], b = pool[i];
        for (int c = a + 1; c <= b; ++c) start[c] = i;
    }
}

// block per cluster: mean of z rows + cnt + bpool
__global__ void pool_mean(const float* __restrict__ z, const int* __restrict__ start,
                          const int* __restrict__ batch, float* __restrict__ p,
                          int* __restrict__ cnt_out, int* __restrict__ bpool) {
    int c = blockIdx.x, t = threadIdx.x;  // 64 threads
    int s = start[c], e = start[c + 1];
    int cnt = e - s;
    const float4* z4 = (const float4*)z;
    float ax = 0.f, ay = 0.f, az = 0.f, aw = 0.f;
    for (int i = s; i < e; ++i) {
        float4 v = z4[(size_t)i * 64 + t];
        ax += v.x; ay += v.y; az += v.z; aw += v.w;
    }
    float inv = 1.0f / (float)max(cnt, 1);
    float4 o; o.x = ax * inv; o.y = ay * inv; o.z = az * inv; o.w = aw * inv;
    ((float4*)p)[(size_t)c * 64 + t] = o;
    if (t == 0) {
        cnt_out[c] = cnt;
        int sb = 0;
        for (int i = s; i < e; ++i) sb += batch[i];
        bpool[c] = (int)rintf((float)sb * inv);  // exact integer -> round safe
    }
}

__global__ void pool_b_accum(const float* __restrict__ z, const int* __restrict__ bpool,
                             float* __restrict__ pb) {
    int c = blockIdx.x, t = threadIdx.x;  // 64 threads
    int b = bpool[c];
#pragma unroll
    for (int j = 0; j < 4; ++j)
        atomicAdd(&pb[b * 256 + t * 4 + j], z[(size_t)c * 256 + t * 4 + j]);
}

__global__ void cntB_accum(const int* __restrict__ bpool, int* __restrict__ cntB, int n) {
    int c = blockIdx.x * blockDim.x + threadIdx.x;
    if (c < n) atomicAdd(&cntB[bpool[c]], 1);
}

// ---------------- heads ----------------

// logits0 + softmax + write x0 to d_out + build xb = [x0 | x_pool1]
__global__ void head0(const float* __restrict__ xp, const float* __restrict__ linW,
                      const float* __restrict__ linb, const float* __restrict__ xpool1,
                      float* __restrict__ outp, float* __restrict__ xb) {
    int r = blockIdx.x, t = threadIdx.x;  // 64 threads
    __shared__ float xr[256];
    __shared__ float lg[16];
    __shared__ float ex[16];
#pragma unroll
    for (int j = 0; j < 4; ++j) xr[t + 64 * j] = xp[(size_t)r * 256 + t + 64 * j];
    __syncthreads();
    if (t < 16) {
        float acc = linb[t];
        for (int k = 0; k < 256; ++k) acc += xr[k] * linW[k * 16 + t];
        lg[t] = acc;
    }
    __syncthreads();
    if (t < 16) {
        float mx = lg[0];
#pragma unroll
        for (int c = 1; c < 16; ++c) mx = fmaxf(mx, lg[c]);
        ex[t] = expf(lg[t] - mx);
    }
    __syncthreads();
    if (t < 16) {
        float sum = 0.f;
#pragma unroll
        for (int c = 0; c < 16; ++c) sum += ex[c];
        float pv = ex[t] / sum;
        outp[(size_t)r * 16 + t] = pv;
        xb[(size_t)r * 17 + t] = pv;
    }
    if (t == 16) xb[(size_t)r * 17 + 16] = xpool1[r];
}

// final: mean(pb) -> layer2 GEMM+BN -> logits -> softmax -> d_out tail
__global__ void head1(const float* __restrict__ pb, const int* __restrict__ cntB,
                      const float* __restrict__ W, const float* __restrict__ bias,
                      const float* __restrict__ gam, const float* __restrict__ bet,
                      const float* __restrict__ mu, const float* __restrict__ var,
                      const float* __restrict__ linW, const float* __restrict__ linb,
                      float* __restrict__ outp) {
    int b = blockIdx.x, t = threadIdx.x;  // 256 threads
    __shared__ float pr[256];
    __shared__ float yr[256];
    __shared__ float lg[16];
    __shared__ float ex[16];
    int c = cntB[b];
    float inv = 1.0f / (float)max(c, 1);
    pr[t] = pb[b * 256 + t] * inv;
    __syncthreads();
    float acc = bias[t];
    for (int k = 0; k < 256; ++k) acc += pr[k] * W[k * 256 + t];
    float s = gam[t] * rsqrtf(var[t] + EPSc);
    acc = (acc - mu[t]) * s + bet[t];
    if (c == 0) acc = 0.f;
    yr[t] = acc;
    __syncthreads();
    if (t < 16) {
        float l = linb[t];
        for (int k = 0; k < 256; ++k) l += yr[k] * linW[k * 16 + t];
        lg[t] = l;
    }
    __syncthreads();
    if (t < 16) {
        float mx = lg[0];
#pragma unroll
        for (int cc = 1; cc < 16; ++cc) mx = fmaxf(mx, lg[cc]);
        ex[t] = expf(lg[t] - mx);
    }
    __syncthreads();
    if (t < 16) {
        float sum = 0.f;
#pragma unroll
        for (int cc = 0; cc < 16; ++cc) sum += ex[cc];
        outp[48000 + b * 16 + t] = ex[t] / sum;
    }
}

// ---------------- launch ----------------

extern "C" void kernel_launch(void* const* d_in, const int* in_sizes, int n_in,
                              void* d_out, int out_size, void* d_ws, size_t ws_size,
                              hipStream_t stream) {
    const float* x       = (const float*)d_in[0];
    const float* x_pool1 = (const float*)d_in[1];
    const float* W_in0   = (const float*)d_in[2];
    const float* W_h0    = (const float*)d_in[3];
    const float* b0      = (const float*)d_in[4];
    const float* g0      = (const float*)d_in[5];
    const float* be0     = (const float*)d_in[6];
    const float* m0      = (const float*)d_in[7];
    const float* v0      = (const float*)d_in[8];
    const float* W_in1   = (const float*)d_in[9];
    const float* W_h1    = (const float*)d_in[10];
    const float* b1      = (const float*)d_in[11];
    const float* g1      = (const float*)d_in[12];
    const float* be1     = (const float*)d_in[13];
    const float* m1      = (const float*)d_in[14];
    const float* v1      = (const float*)d_in[15];
    const float* linW0   = (const float*)d_in[16];
    const float* linb0   = (const float*)d_in[17];
    const float* linW1   = (const float*)d_in[18];
    const float* linb1   = (const float*)d_in[19];
    const int*   ei      = (const int*)d_in[20];
    const int*   batch   = (const int*)d_in[21];
    const int*   pool1   = (const int*)d_in[22];
    const int*   eip     = (const int*)d_in[23];
    float* outp = (float*)d_out;

    // carve workspace (256B-aligned)
    char* p = (char*)d_ws;
    auto carve = [&](size_t bytes) -> void* {
        void* r = (void*)p;
        p += (bytes + 255) & ~(size_t)255;
        return r;
    };
    int*   deg0   = (int*)  carve((size_t)N0c * 4);
    int*   tmp0   = (int*)  carve((size_t)N0c * 4);
    int*   rp0    = (int*)  carve((size_t)(N0c + 1) * 4);
    float* dinv0  = (float*)carve((size_t)N0c * 4);
    int*   blkSum = (int*)  carve(256 * 4);
    int*   blkOff = (int*)  carve(256 * 4);
    int2*  csw0   = (int2*) carve((size_t)E0c * 8);
    float* bufA   = (float*)carve((size_t)N0c * Hc * 4);
    float* bufB   = (float*)carve((size_t)N0c * Hc * 4);
    int*   start0 = (int*)  carve((size_t)(N1c + 1) * 4);
    int*   cnt0   = (int*)  carve((size_t)N1c * 4);
    float* pmean  = (float*)carve((size_t)N1c * Hc * 4);
    float* xp     = (float*)carve((size_t)N1c * Hc * 4);
    float* xb     = (float*)carve((size_t)N1c * 17 * 4);
    float* zb17   = (float*)carve((size_t)N1c * 17 * 4);
    int*   bpool  = (int*)  carve((size_t)N1c * 4);
    int*   deg1   = (int*)  carve((size_t)N1c * 4);
    int*   tmp1   = (int*)  carve((size_t)N1c * 4);
    int*   rp1    = (int*)  carve((size_t)(N1c + 1) * 4);
    float* dinv1  = (float*)carve((size_t)N1c * 4);
    int2*  csw1   = (int2*) carve((size_t)E1c * 8);
    float* zbb    = (float*)carve((size_t)N1c * Hc * 4);
    float* hbb    = (float*)carve((size_t)N1c * Hc * 4);
    float* pb     = (float*)carve((size_t)Bc * Hc * 4);
    int*   cntB   = (int*)  carve((size_t)Bc * 4);

    // zero-init accumulators (ws is poisoned every call)
    hipMemsetAsync(deg0, 0, (size_t)N0c * 4, stream);
    hipMemsetAsync(tmp0, 0, (size_t)N0c * 4, stream);
    hipMemsetAsync(deg1, 0, (size_t)N1c * 4, stream);
    hipMemsetAsync(tmp1, 0, (size_t)N1c * 4, stream);
    hipMemsetAsync(pb,   0, (size_t)Bc * Hc * 4, stream);
    hipMemsetAsync(cntB, 0, (size_t)Bc * 4, stream);

    const int* src0 = ei;
    const int* dst0 = ei + E0c;
    const int* src1 = eip;
    const int* dst1 = eip + E1c;

    // ---- graph 0 CSR ----
    count_deg<<<cdiv_i(E0c, 256), 256, 0, stream>>>(dst0, E0c, deg0);
    calc_dinv<<<cdiv_i(N0c, 256), 256, 0, stream>>>(deg0, dinv0, N0c);
    int nb0 = cdiv_i(N0c, 256);
    scan_block<<<nb0, 256, 0, stream>>>(deg0, N0c, rp0, blkSum);
    scan_sums<<<1, 256, 0, stream>>>(blkSum, nb0, blkOff, rp0, N0c);
    scan_add<<<nb0, 256, 0, stream>>>(rp0, N0c, blkOff);
    fill_csr<<<cdiv_i(E0c, 256), 256, 0, stream>>>(src0, dst0, E0c, rp0, tmp0, dinv0, csw0);

    // ---- phase A: 3 GCN layers on N0, aggregate-first ----
    agg_wide<32, 4><<<4 * cdiv_i(N0c, 4), 256, 0, stream>>>(x, rp0, csw0, dinv0, bufA, N0c);
    gemm_bn<128, true, false><<<dim3(cdiv_i(N0c, 64), 4), 256, 0, stream>>>(
        bufA, W_in0, b0, g0, be0, m0, v0, nullptr, bufB, N0c);
    agg_wide<64, 8><<<8 * cdiv_i(N0c, 4), 256, 0, stream>>>(bufB, rp0, csw0, dinv0, bufA, N0c);
    gemm_bn<256, true, false><<<dim3(cdiv_i(N0c, 64), 4), 256, 0, stream>>>(
        bufA, W_h0, b0 + Hc, g0 + Hc, be0 + Hc, m0 + Hc, v0 + Hc, nullptr, bufB, N0c);
    agg_wide<64, 8><<<8 * cdiv_i(N0c, 4), 256, 0, stream>>>(bufB, rp0, csw0, dinv0, bufA, N0c);

    // layer 2: pool BEFORE GEMM (affine reorder); zero empty clusters in epilogue
    seg_starts<<<cdiv_i(N0c + 1, 256), 256, 0, stream>>>(pool1, N0c, N1c, start0);
    pool_mean<<<N1c, 64, 0, stream>>>(bufA, start0, batch, pmean, cnt0, bpool);
    gemm_bn<256, false, true><<<dim3(cdiv_i(N1c, 64), 4), 256, 0, stream>>>(
        pmean, W_h0 + Hc * Hc, b0 + 2 * Hc, g0 + 2 * Hc, be0 + 2 * Hc, m0 + 2 * Hc,
        v0 + 2 * Hc, cnt0, xp, N1c);

    // head0: logits + softmax -> d_out[0:48000], xb = [x0 | x_pool1]
    head0<<<N1c, 64, 0, stream>>>(xp, linW0, linb0, x_pool1, outp, xb);

    // ---- graph 1 CSR ----
    count_deg<<<cdiv_i(E1c, 256), 256, 0, stream>>>(dst1, E1c, deg1);
    calc_dinv<<<cdiv_i(N1c, 256), 256, 0, stream>>>(deg1, dinv1, N1c);
    int nb1 = cdiv_i(N1c, 256);
    scan_block<<<nb1, 256, 0, stream>>>(deg1, N1c, rp1, blkSum);
    scan_sums<<<1, 256, 0, stream>>>(blkSum, nb1, blkOff, rp1, N1c);
    scan_add<<<nb1, 256, 0, stream>>>(rp1, N1c, blkOff);
    fill_csr<<<cdiv_i(E1c, 256), 256, 0, stream>>>(src1, dst1, E1c, rp1, tmp1, dinv1, csw1);

    // ---- phase B: 3 GCN layers on N1 ----
    agg_small<<<N1c, 64, 0, stream>>>(xb, rp1, csw1, dinv1, zb17, 17);
    gemm17_bn_relu<<<N1c, 256, 0, stream>>>(zb17, W_in1, b1, g1, be1, m1, v1, hbb);
    agg_wide<64, 8><<<8 * cdiv_i(N1c, 4), 256, 0, stream>>>(hbb, rp1, csw1, dinv1, zbb, N1c);
    gemm_bn<256, true, false><<<dim3(cdiv_i(N1c, 64), 4), 256, 0, stream>>>(
        zbb, W_h1, b1 + Hc, g1 + Hc, be1 + Hc, m1 + Hc, v1 + Hc, nullptr, hbb, N1c);
    agg_wide<64, 8><<<8 * cdiv_i(N1c, 4), 256, 0, stream>>>(hbb, rp1, csw1, dinv1, zbb, N1c);

    // layer 2: pool to B graphs BEFORE GEMM (bpool is NOT sorted -> atomics)
    pool_b_accum<<<N1c, 64, 0, stream>>>(zbb, bpool, pb);
    cntB_accum<<<cdiv_i(N1c, 256), 256, 0, stream>>>(bpool, cntB, N1c);

    // head1: layer2 GEMM+BN + logits + softmax -> d_out[48000:48256]
    head1<<<Bc, 256, 0, stream>>>(pb, cntB, W_h1 + Hc * Hc, b1 + 2 * Hc, g1 + 2 * Hc,
                                  be1 + 2 * Hc, m1 + 2 * Hc, v1 + 2 * Hc, linW1, linb1,
                                  outp);
}